// Round 6
// baseline (59.766 us; speedup 1.0000x reference)
//
#include <hip/hip_runtime.h>
#include <stdint.h>

#define B 4
#define N 16384
#define S 2048
#define C 64
#define K 64
#define OC 66
#define R2 0.01f
#define NXCD 8

typedef float f32x4 __attribute__((ext_vector_type(4)));   // nontemporal-safe

// ---------------------------------------------------------------------------
// Kernel 1 (prep, heterogeneous grid):
//   blocks [0, 1024):    transpose features (B,C,N) -> ft (B,N,C)
//   blocks [1024, 3072): ball-query scan, one wave per query -> idx[B*S][K],
//                        plus output channels 0,1 (grouped_xyz).
// Transpose streaming and latency-bound scans co-schedule on the CUs;
// scan stragglers hide under transpose BW instead of serializing.
// ---------------------------------------------------------------------------
__global__ __launch_bounds__(256) void prep_kernel(const float* __restrict__ f,
                                                   const float* __restrict__ xyz,
                                                   const float* __restrict__ new_xyz,
                                                   const int* __restrict__ pointsnum,
                                                   float* __restrict__ ft,
                                                   int* __restrict__ idx,
                                                   float* __restrict__ out) {
    __shared__ float tile[64 * 65];
    __shared__ int   s_idx[4][K];

    const int t = threadIdx.x;

    if (blockIdx.x < 1024) {
        // ---------------- transpose path ----------------
        const int n0 = (blockIdx.x & 255) * 64;
        const int b  = blockIdx.x >> 8;

        const int nl = t & 63, cl = t >> 6;
        #pragma unroll
        for (int cc = cl; cc < 64; cc += 4) {
            tile[cc * 65 + nl] = __builtin_nontemporal_load(&f[((size_t)b * C + cc) * N + n0 + nl]);
        }
        __syncthreads();

        const int cl2 = t & 63, nl2 = t >> 6;
        #pragma unroll
        for (int nn = nl2; nn < 64; nn += 4) {
            ft[((size_t)b * N + n0 + nn) * C + cl2] = tile[cl2 * 65 + nn];
        }
        return;
    }

    // ---------------- scan path (one wave per query) ----------------
    const int lane = t & 63;
    const int wu   = __builtin_amdgcn_readfirstlane(t >> 6);
    const int q0   = (int)(blockIdx.x - 1024) * 4;
    const int b    = q0 >> 11;             // / S (S=2048)
    const int q    = q0 + wu;
    const int s    = (q0 & (S - 1)) + wu;

    const float qx = new_xyz[(size_t)q * 2 + 0];
    const float qy = new_xyz[(size_t)q * 2 + 1];
    const float* __restrict__ xb = xyz + (size_t)b * N * 2;

    int pn = pointsnum[b];
    pn = pn < 0 ? 0 : (pn > N ? N : pn);
    int cnt = 0;
    for (int base = 0; base < pn && cnt < K; base += 256) {
        float2 p[4];
        #pragma unroll
        for (int u = 0; u < 4; ++u) {
            int i  = base + u * 64 + lane;
            int ic = i < N ? i : N - 1;              // always-valid address
            p[u] = *(const float2*)&xb[(size_t)ic * 2];
        }
        #pragma unroll
        for (int u = 0; u < 4; ++u) {
            const int i = base + u * 64 + lane;
            bool ok = false;
            if (i < pn) {
                // match numpy f32 rounding exactly: no FMA contraction
                const float dx = __fsub_rn(qx, p[u].x);
                const float dy = __fsub_rn(qy, p[u].y);
                const float d2 = __fadd_rn(__fmul_rn(dx, dx), __fmul_rn(dy, dy));
                ok = d2 < R2;
            }
            const unsigned long long m = __ballot(ok);
            if (ok) {
                const int pos = cnt + __popcll(m & ((1ull << lane) - 1ull));
                if (pos < K) s_idx[wu][pos] = i;
            }
            cnt += __popcll(m);
        }
    }
    const int found = cnt < K ? cnt : K;
    const int first = (found > 0) ? s_idx[wu][0] : 0;   // pad value (0 if none)
    const int id    = (lane < found) ? s_idx[wu][lane] : first;

    idx[(size_t)q * K + lane] = id;                     // coalesced 256B

    // channels 0,1: grouped_xyz = xyz[id] - new_xyz[s]
    const size_t SK = (size_t)S * K;
    const float2 pxy = *(const float2*)&xb[(size_t)id * 2];
    float* ob = out + ((size_t)b * OC) * SK + (size_t)s * K;
    __builtin_nontemporal_store(pxy.x - qx, ob + lane);
    __builtin_nontemporal_store(pxy.y - qy, ob + SK + lane);
}

// ---------------------------------------------------------------------------
// Kernel 2 (gather): uniform streaming, perfectly balanced. 4 consecutive
// queries per block (same b), XCD swizzle for ft L2 locality, gathers are
// 64B-line chunks, stores staged through LDS -> 1 KB contiguous per instr.
// ---------------------------------------------------------------------------
__global__ __launch_bounds__(256) void gather_kernel(const float* __restrict__ ft,
                                                     const int* __restrict__ idx,
                                                     float* __restrict__ out) {
    __shared__ float tile[4][16][K];   // [q][c-in-chunk][k]  (16 KB)

    const int t    = threadIdx.x;
    const int lane = t & 63;
    const int wu   = __builtin_amdgcn_readfirstlane(t >> 6);

    // bijective XCD swizzle: nwg = 2048, 2048 % 8 == 0
    const int nwg = (B * S) / 4;
    const int bid = blockIdx.x;
    const int swz = (bid & (NXCD - 1)) * (nwg / NXCD) + (bid >> 3);

    const int q0 = swz * 4;
    const int b  = q0 >> 11;
    const int s0 = q0 & (S - 1);
    const int q  = q0 + wu;

    const int id = idx[(size_t)q * K + lane];           // coalesced 256B
    const float* __restrict__ row = ft + ((size_t)b * N + id) * C;

    const size_t SK = (size_t)S * K;
    const int ql = lane >> 4;              // store-phase: query sub-index 0..3
    const int kq = (lane & 15) * 4;        // store-phase: k base

    #pragma unroll
    for (int cc = 0; cc < 4; ++cc) {       // channels 16*cc .. 16*cc+15
        const float4* r4 = (const float4*)(row + 16 * cc);
        const float4 g0 = r4[0], g1 = r4[1], g2 = r4[2], g3 = r4[3];

        __syncthreads();   // previous chunk's tile reads are done
        tile[wu][ 0][lane] = g0.x; tile[wu][ 1][lane] = g0.y;
        tile[wu][ 2][lane] = g0.z; tile[wu][ 3][lane] = g0.w;
        tile[wu][ 4][lane] = g1.x; tile[wu][ 5][lane] = g1.y;
        tile[wu][ 6][lane] = g1.z; tile[wu][ 7][lane] = g1.w;
        tile[wu][ 8][lane] = g2.x; tile[wu][ 9][lane] = g2.y;
        tile[wu][10][lane] = g2.z; tile[wu][11][lane] = g2.w;
        tile[wu][12][lane] = g3.x; tile[wu][13][lane] = g3.y;
        tile[wu][14][lane] = g3.z; tile[wu][15][lane] = g3.w;
        __syncthreads();

        // each wave stores 4 channels; one instr = 64 lanes x float4 = 1 KB
        #pragma unroll
        for (int j = 0; j < 4; ++j) {
            const int c16 = 4 * wu + j;
            const int c   = 16 * cc + c16;
            f32x4 vv = *(const f32x4*)&tile[ql][c16][kq];
            float* bp = out + ((size_t)b * OC + 2 + c) * SK + (size_t)s0 * K;
            __builtin_nontemporal_store(vv, ((f32x4*)bp) + lane);
        }
    }
}

// ---------------------------------------------------------------------------
// Fallback: fused single-kernel path (R5 version) if ws is too small.
// ---------------------------------------------------------------------------
template <bool USE_T>
__global__ __launch_bounds__(256) void qag_kernel(const float* __restrict__ xyz,
                                                  const float* __restrict__ new_xyz,
                                                  const float* __restrict__ feat,
                                                  const float* __restrict__ ft,
                                                  const int* __restrict__ pointsnum,
                                                  float* __restrict__ out) {
    __shared__ int   s_idx[4][K];
    __shared__ float tile[4][16][K];

    const int t    = threadIdx.x;
    const int lane = t & 63;
    const int wu   = __builtin_amdgcn_readfirstlane(t >> 6);

    const int nwg = (B * S) / 4;
    const int bid = blockIdx.x;
    const int swz = (bid & (NXCD - 1)) * (nwg / NXCD) + (bid >> 3);

    const int q0   = swz * 4;
    const int b    = q0 >> 11;
    const int s0   = q0 & (S - 1);
    const int q    = q0 + wu;
    const int s    = s0 + wu;

    const float qx = new_xyz[(size_t)q * 2 + 0];
    const float qy = new_xyz[(size_t)q * 2 + 1];
    const float* __restrict__ xb = xyz + (size_t)b * N * 2;

    int pn = pointsnum[b];
    pn = pn < 0 ? 0 : (pn > N ? N : pn);
    int cnt = 0;
    for (int base = 0; base < pn && cnt < K; base += 256) {
        float2 p[4];
        #pragma unroll
        for (int u = 0; u < 4; ++u) {
            int i  = base + u * 64 + lane;
            int ic = i < N ? i : N - 1;
            p[u] = *(const float2*)&xb[(size_t)ic * 2];
        }
        #pragma unroll
        for (int u = 0; u < 4; ++u) {
            const int i = base + u * 64 + lane;
            bool ok = false;
            if (i < pn) {
                const float dx = __fsub_rn(qx, p[u].x);
                const float dy = __fsub_rn(qy, p[u].y);
                const float d2 = __fadd_rn(__fmul_rn(dx, dx), __fmul_rn(dy, dy));
                ok = d2 < R2;
            }
            const unsigned long long m = __ballot(ok);
            if (ok) {
                const int pos = cnt + __popcll(m & ((1ull << lane) - 1ull));
                if (pos < K) s_idx[wu][pos] = i;
            }
            cnt += __popcll(m);
        }
    }
    const int found = cnt < K ? cnt : K;
    const int first = (found > 0) ? s_idx[wu][0] : 0;
    const int id    = (lane < found) ? s_idx[wu][lane] : first;

    const size_t SK = (size_t)S * K;
    const float2 pxy = *(const float2*)&xb[(size_t)id * 2];
    {
        float* ob = out + ((size_t)b * OC) * SK + (size_t)s * K;
        __builtin_nontemporal_store(pxy.x - qx, ob + lane);
        __builtin_nontemporal_store(pxy.y - qy, ob + SK + lane);
    }

    const float* __restrict__ row = USE_T ? (ft + ((size_t)b * N + id) * C) : nullptr;
    const float* __restrict__ fb  = feat + (size_t)b * C * N;
    const int ql = lane >> 4;
    const int kq = (lane & 15) * 4;

    #pragma unroll
    for (int cc = 0; cc < 4; ++cc) {
        float4 g0, g1, g2, g3;
        if (USE_T) {
            const float4* r4 = (const float4*)(row + 16 * cc);
            g0 = r4[0]; g1 = r4[1]; g2 = r4[2]; g3 = r4[3];
        } else {
            const int c0 = 16 * cc;
            g0.x = fb[(size_t)(c0 +  0) * N + id]; g0.y = fb[(size_t)(c0 +  1) * N + id];
            g0.z = fb[(size_t)(c0 +  2) * N + id]; g0.w = fb[(size_t)(c0 +  3) * N + id];
            g1.x = fb[(size_t)(c0 +  4) * N + id]; g1.y = fb[(size_t)(c0 +  5) * N + id];
            g1.z = fb[(size_t)(c0 +  6) * N + id]; g1.w = fb[(size_t)(c0 +  7) * N + id];
            g2.x = fb[(size_t)(c0 +  8) * N + id]; g2.y = fb[(size_t)(c0 +  9) * N + id];
            g2.z = fb[(size_t)(c0 + 10) * N + id]; g2.w = fb[(size_t)(c0 + 11) * N + id];
            g3.x = fb[(size_t)(c0 + 12) * N + id]; g3.y = fb[(size_t)(c0 + 13) * N + id];
            g3.z = fb[(size_t)(c0 + 14) * N + id]; g3.w = fb[(size_t)(c0 + 15) * N + id];
        }

        __syncthreads();
        tile[wu][ 0][lane] = g0.x; tile[wu][ 1][lane] = g0.y;
        tile[wu][ 2][lane] = g0.z; tile[wu][ 3][lane] = g0.w;
        tile[wu][ 4][lane] = g1.x; tile[wu][ 5][lane] = g1.y;
        tile[wu][ 6][lane] = g1.z; tile[wu][ 7][lane] = g1.w;
        tile[wu][ 8][lane] = g2.x; tile[wu][ 9][lane] = g2.y;
        tile[wu][10][lane] = g2.z; tile[wu][11][lane] = g2.w;
        tile[wu][12][lane] = g3.x; tile[wu][13][lane] = g3.y;
        tile[wu][14][lane] = g3.z; tile[wu][15][lane] = g3.w;
        __syncthreads();

        #pragma unroll
        for (int j = 0; j < 4; ++j) {
            const int c16 = 4 * wu + j;
            const int c   = 16 * cc + c16;
            f32x4 vv = *(const f32x4*)&tile[ql][c16][kq];
            float* bp = out + ((size_t)b * OC + 2 + c) * SK + (size_t)s0 * K;
            __builtin_nontemporal_store(vv, ((f32x4*)bp) + lane);
        }
    }
}

extern "C" void kernel_launch(void* const* d_in, const int* in_sizes, int n_in,
                              void* d_out, int out_size, void* d_ws, size_t ws_size,
                              hipStream_t stream) {
    const float* xyz       = (const float*)d_in[0];
    const float* new_xyz   = (const float*)d_in[1];
    const float* feat      = (const float*)d_in[2];
    const int*   pointsnum = (const int*)d_in[3];
    float*       out       = (float*)d_out;

    const size_t ft_bytes  = (size_t)B * N * C * sizeof(float);       // 16.8 MB
    const size_t idx_bytes = (size_t)B * S * K * sizeof(int);         //  2.1 MB

    if (ws_size >= ft_bytes + idx_bytes) {
        float* ft  = (float*)d_ws;
        int*   idx = (int*)((char*)d_ws + ft_bytes);
        prep_kernel<<<1024 + B * S / 4, 256, 0, stream>>>(feat, xyz, new_xyz, pointsnum, ft, idx, out);
        gather_kernel<<<B * S / 4, 256, 0, stream>>>(ft, idx, out);
    } else if (ws_size >= ft_bytes) {
        float* ft = (float*)d_ws;
        // old 2-kernel fused path
        prep_kernel<<<1024, 256, 0, stream>>>(feat, xyz, new_xyz, pointsnum, ft, nullptr, out); // transpose blocks only
        qag_kernel<true><<<B * S / 4, 256, 0, stream>>>(xyz, new_xyz, feat, ft, pointsnum, out);
    } else {
        qag_kernel<false><<<B * S / 4, 256, 0, stream>>>(xyz, new_xyz, feat, nullptr, pointsnum, out);
    }
}

// Round 7
// 55.339 us; speedup vs baseline: 1.0800x; 1.0800x over previous
//
#include <hip/hip_runtime.h>
#include <stdint.h>

#define B 4
#define N 16384
#define S 2048
#define C 64
#define K 64
#define OC 66
#define R2 0.01f
#define NXCD 8
#define TP 1089   // tile pitch per query: 64*17 + 1 floats (bank-skewed)

typedef float f32x4 __attribute__((ext_vector_type(4)));   // nontemporal-safe

// ---------------------------------------------------------------------------
// Kernel 1: transpose features (B,C,N) -> ft (B,N,C) so a point's 64
// channels are one contiguous 256B run (4 cache lines).
// ---------------------------------------------------------------------------
__global__ __launch_bounds__(256) void transpose_kernel(const float* __restrict__ f,
                                                        float* __restrict__ ft) {
    __shared__ float tile[64 * 65];
    const int n0 = blockIdx.x * 64;
    const int b  = blockIdx.y;
    const int t  = threadIdx.x;

    const int nl = t & 63, cl = t >> 6;
    #pragma unroll
    for (int cc = cl; cc < 64; cc += 4) {
        tile[cc * 65 + nl] = __builtin_nontemporal_load(&f[((size_t)b * C + cc) * N + n0 + nl]);
    }
    __syncthreads();

    const int cl2 = t & 63, nl2 = t >> 6;
    #pragma unroll
    for (int nn = nl2; nn < 64; nn += 4) {
        ft[((size_t)b * N + n0 + nn) * C + cl2] = tile[cl2 * 65 + nn];
    }
}

// ---------------------------------------------------------------------------
// Kernel 2: fused ball-query + group + concat (R5 structure, NEW gather).
// One wave per query, 4 queries/block, XCD swizzle.
// Gather: 4 LANES PER POINT-ROW -> each load instruction reads 16 points x
// one 64B line, every line touched exactly once and fully consumed (256
// line-touches/wave vs 1024 in the old lane-owns-row pattern). This attacks
// the L1 scattered-request serialization that ~50us was invariant under.
// ---------------------------------------------------------------------------
__global__ __launch_bounds__(256) void qag2_kernel(const float* __restrict__ xyz,
                                                   const float* __restrict__ new_xyz,
                                                   const float* __restrict__ ft,
                                                   const int* __restrict__ pointsnum,
                                                   float* __restrict__ out) {
    __shared__ int   s_idx[4][K];          // per-wave padded index list
    __shared__ float tile[4 * TP];         // [q]: 64 points x pitch17  (17.4 KB)

    const int t    = threadIdx.x;
    const int lane = t & 63;
    const int wu   = __builtin_amdgcn_readfirstlane(t >> 6);

    // bijective XCD swizzle: nwg = 2048, 2048 % 8 == 0
    const int nwg = (B * S) / 4;
    const int bid = blockIdx.x;
    const int swz = (bid & (NXCD - 1)) * (nwg / NXCD) + (bid >> 3);

    const int q0 = swz * 4;
    const int b  = q0 >> 11;               // / S
    const int s0 = q0 & (S - 1);
    const int q  = q0 + wu;
    const int s  = s0 + wu;

    const float qx = new_xyz[(size_t)q * 2 + 0];
    const float qy = new_xyz[(size_t)q * 2 + 1];
    const float* __restrict__ xb = xyz + (size_t)b * N * 2;

    // ---- Phase 1: ordered ball-query scan (per-wave, 4 loads in flight) ----
    int pn = pointsnum[b];
    pn = pn < 0 ? 0 : (pn > N ? N : pn);
    int cnt = 0;
    for (int base = 0; base < pn && cnt < K; base += 256) {
        float2 p[4];
        #pragma unroll
        for (int u = 0; u < 4; ++u) {
            int i  = base + u * 64 + lane;
            int ic = i < N ? i : N - 1;
            p[u] = *(const float2*)&xb[(size_t)ic * 2];
        }
        #pragma unroll
        for (int u = 0; u < 4; ++u) {
            const int i = base + u * 64 + lane;
            bool ok = false;
            if (i < pn) {
                // match numpy f32 rounding exactly: no FMA contraction
                const float dx = __fsub_rn(qx, p[u].x);
                const float dy = __fsub_rn(qy, p[u].y);
                const float d2 = __fadd_rn(__fmul_rn(dx, dx), __fmul_rn(dy, dy));
                ok = d2 < R2;
            }
            const unsigned long long m = __ballot(ok);
            if (ok) {
                const int pos = cnt + __popcll(m & ((1ull << lane) - 1ull));
                if (pos < K) s_idx[wu][pos] = i;
            }
            cnt += __popcll(m);
        }
    }
    const int found = cnt < K ? cnt : K;
    const int first = (found > 0) ? s_idx[wu][0] : 0;
    const int id    = (lane < found) ? s_idx[wu][lane] : first;
    s_idx[wu][lane] = id;                  // padded list (same-wave use only)

    // ---- channels 0,1: grouped_xyz = xyz[id] - new_xyz[s] ----
    const size_t SK = (size_t)S * K;
    const float2 pxy = *(const float2*)&xb[(size_t)id * 2];
    {
        float* ob = out + ((size_t)b * OC) * SK + (size_t)s * K;
        __builtin_nontemporal_store(pxy.x - qx, ob + lane);
        __builtin_nontemporal_store(pxy.y - qy, ob + SK + lane);
    }

    // ---- Phase 2: gather (4 lanes/row) -> LDS transpose -> 1KB NT stores ----
    const int kk = lane >> 2;              // gather: point-sub 0..15
    const int c2 = lane & 3;               // gather: float4 slot in 16-ch chunk
    const int ql = lane >> 4;              // store: query sub-index 0..3
    const int m  = lane & 15;              // store: k group
    const float* __restrict__ ftb = ft + (size_t)b * N * C;

    #pragma unroll
    for (int cc = 0; cc < 4; ++cc) {       // 16-channel chunks
        f32x4 v[4];
        #pragma unroll
        for (int g = 0; g < 4; ++g) {
            const int p  = g * 16 + kk;                 // point 0..63
            const int ip = s_idx[wu][p];                // 16 addrs, broadcast x4
            v[g] = *(const f32x4*)&ftb[(size_t)ip * C + cc * 16 + c2 * 4];
        }

        __syncthreads();   // previous chunk's tile reads are done
        #pragma unroll
        for (int g = 0; g < 4; ++g) {
            const int p = g * 16 + kk;
            *(f32x4*)&tile[wu * TP + p * 17 + c2 * 4] = v[g];   // b128, ~floor
        }
        __syncthreads();

        // wave stores 4 channels of the chunk; 1 instr = 1 KB contiguous
        #pragma unroll
        for (int j = 0; j < 4; ++j) {
            const int cw = 4 * wu + j;                  // channel in chunk
            f32x4 vv;
            vv.x = tile[ql * TP + (4 * m + 0) * 17 + cw];
            vv.y = tile[ql * TP + (4 * m + 1) * 17 + cw];
            vv.z = tile[ql * TP + (4 * m + 2) * 17 + cw];
            vv.w = tile[ql * TP + (4 * m + 3) * 17 + cw];
            float* bp = out + ((size_t)b * OC + 2 + cc * 16 + cw) * SK + (size_t)s0 * K;
            __builtin_nontemporal_store(vv, ((f32x4*)bp) + lane);
        }
    }
}

// ---------------------------------------------------------------------------
// Fallback (tiny ws): fused kernel gathering directly from (B,C,N) feat.
// ---------------------------------------------------------------------------
__global__ __launch_bounds__(256) void qag_fallback(const float* __restrict__ xyz,
                                                    const float* __restrict__ new_xyz,
                                                    const float* __restrict__ feat,
                                                    const int* __restrict__ pointsnum,
                                                    float* __restrict__ out) {
    __shared__ int s_idx[4][K];

    const int t    = threadIdx.x;
    const int lane = t & 63;
    const int wu   = __builtin_amdgcn_readfirstlane(t >> 6);
    const int q0   = blockIdx.x * 4;
    const int b    = q0 >> 11;
    const int q    = q0 + wu;
    const int s    = (q0 & (S - 1)) + wu;

    const float qx = new_xyz[(size_t)q * 2 + 0];
    const float qy = new_xyz[(size_t)q * 2 + 1];
    const float* __restrict__ xb = xyz + (size_t)b * N * 2;

    int pn = pointsnum[b];
    pn = pn < 0 ? 0 : (pn > N ? N : pn);
    int cnt = 0;
    for (int base = 0; base < pn && cnt < K; base += 256) {
        float2 p[4];
        #pragma unroll
        for (int u = 0; u < 4; ++u) {
            int i  = base + u * 64 + lane;
            int ic = i < N ? i : N - 1;
            p[u] = *(const float2*)&xb[(size_t)ic * 2];
        }
        #pragma unroll
        for (int u = 0; u < 4; ++u) {
            const int i = base + u * 64 + lane;
            bool ok = false;
            if (i < pn) {
                const float dx = __fsub_rn(qx, p[u].x);
                const float dy = __fsub_rn(qy, p[u].y);
                const float d2 = __fadd_rn(__fmul_rn(dx, dx), __fmul_rn(dy, dy));
                ok = d2 < R2;
            }
            const unsigned long long mm = __ballot(ok);
            if (ok) {
                const int pos = cnt + __popcll(mm & ((1ull << lane) - 1ull));
                if (pos < K) s_idx[wu][pos] = i;
            }
            cnt += __popcll(mm);
        }
    }
    const int found = cnt < K ? cnt : K;
    const int first = (found > 0) ? s_idx[wu][0] : 0;
    const int id    = (lane < found) ? s_idx[wu][lane] : first;

    const size_t SK = (size_t)S * K;
    const float2 pxy = *(const float2*)&xb[(size_t)id * 2];
    float* ob = out + ((size_t)b * OC) * SK + (size_t)s * K;
    ob[lane]      = pxy.x - qx;
    ob[SK + lane] = pxy.y - qy;

    const float* __restrict__ fb = feat + (size_t)b * C * N;
    for (int c = 0; c < C; ++c) {
        ob[(size_t)(2 + c) * SK + lane] = fb[(size_t)c * N + id];
    }
}

extern "C" void kernel_launch(void* const* d_in, const int* in_sizes, int n_in,
                              void* d_out, int out_size, void* d_ws, size_t ws_size,
                              hipStream_t stream) {
    const float* xyz       = (const float*)d_in[0];
    const float* new_xyz   = (const float*)d_in[1];
    const float* feat      = (const float*)d_in[2];
    const int*   pointsnum = (const int*)d_in[3];
    float*       out       = (float*)d_out;

    const size_t ft_bytes = (size_t)B * N * C * sizeof(float);    // 16.8 MB
    if (ws_size >= ft_bytes) {
        float* ft = (float*)d_ws;
        transpose_kernel<<<dim3(N / 64, B), 256, 0, stream>>>(feat, ft);
        qag2_kernel<<<B * S / 4, 256, 0, stream>>>(xyz, new_xyz, ft, pointsnum, out);
    } else {
        qag_fallback<<<B * S / 4, 256, 0, stream>>>(xyz, new_xyz, feat, pointsnum, out);
    }
}

// Round 8
// 52.267 us; speedup vs baseline: 1.1435x; 1.0588x over previous
//
#include <hip/hip_runtime.h>
#include <stdint.h>

#define B 4
#define N 16384
#define S 2048
#define C 64
#define K 64
#define OC 66
#define R2 0.01f
#define NXCD 8
#define TP 1089   // tile pitch per query: 64*17 + 1 floats (bank-skewed)

typedef float f32x4 __attribute__((ext_vector_type(4)));

// ---------------------------------------------------------------------------
// Kernel 1: transpose features (B,C,N) -> ft (B,N,C) so a point's 64
// channels are one contiguous 256B run (4 cache lines).
// ---------------------------------------------------------------------------
__global__ __launch_bounds__(256) void transpose_kernel(const float* __restrict__ f,
                                                        float* __restrict__ ft) {
    __shared__ float tile[64 * 65];
    const int n0 = blockIdx.x * 64;
    const int b  = blockIdx.y;
    const int t  = threadIdx.x;

    const int nl = t & 63, cl = t >> 6;
    #pragma unroll
    for (int cc = cl; cc < 64; cc += 4) {
        tile[cc * 65 + nl] = __builtin_nontemporal_load(&f[((size_t)b * C + cc) * N + n0 + nl]);
    }
    __syncthreads();

    const int cl2 = t & 63, nl2 = t >> 6;
    #pragma unroll
    for (int nn = nl2; nn < 64; nn += 4) {
        ft[((size_t)b * N + n0 + nn) * C + cl2] = tile[cl2 * 65 + nn];
    }
}

// ---------------------------------------------------------------------------
// Kernel 2: fused ball-query + group + concat. R7 structure EXACTLY, with
// ONE variable changed: all output stores are plain cached stores instead of
// nontemporal (testing the NT-store throughput-ceiling theory for the
// invariant ~49us).
// ---------------------------------------------------------------------------
__global__ __launch_bounds__(256) void qag2_kernel(const float* __restrict__ xyz,
                                                   const float* __restrict__ new_xyz,
                                                   const float* __restrict__ ft,
                                                   const int* __restrict__ pointsnum,
                                                   float* __restrict__ out) {
    __shared__ int   s_idx[4][K];          // per-wave padded index list
    __shared__ float tile[4 * TP];         // [q]: 64 points x pitch17  (17.4 KB)

    const int t    = threadIdx.x;
    const int lane = t & 63;
    const int wu   = __builtin_amdgcn_readfirstlane(t >> 6);

    // bijective XCD swizzle: nwg = 2048, 2048 % 8 == 0
    const int nwg = (B * S) / 4;
    const int bid = blockIdx.x;
    const int swz = (bid & (NXCD - 1)) * (nwg / NXCD) + (bid >> 3);

    const int q0 = swz * 4;
    const int b  = q0 >> 11;               // / S
    const int s0 = q0 & (S - 1);
    const int q  = q0 + wu;
    const int s  = s0 + wu;

    const float qx = new_xyz[(size_t)q * 2 + 0];
    const float qy = new_xyz[(size_t)q * 2 + 1];
    const float* __restrict__ xb = xyz + (size_t)b * N * 2;

    // ---- Phase 1: ordered ball-query scan (per-wave, 4 loads in flight) ----
    int pn = pointsnum[b];
    pn = pn < 0 ? 0 : (pn > N ? N : pn);
    int cnt = 0;
    for (int base = 0; base < pn && cnt < K; base += 256) {
        float2 p[4];
        #pragma unroll
        for (int u = 0; u < 4; ++u) {
            int i  = base + u * 64 + lane;
            int ic = i < N ? i : N - 1;
            p[u] = *(const float2*)&xb[(size_t)ic * 2];
        }
        #pragma unroll
        for (int u = 0; u < 4; ++u) {
            const int i = base + u * 64 + lane;
            bool ok = false;
            if (i < pn) {
                // match numpy f32 rounding exactly: no FMA contraction
                const float dx = __fsub_rn(qx, p[u].x);
                const float dy = __fsub_rn(qy, p[u].y);
                const float d2 = __fadd_rn(__fmul_rn(dx, dx), __fmul_rn(dy, dy));
                ok = d2 < R2;
            }
            const unsigned long long m = __ballot(ok);
            if (ok) {
                const int pos = cnt + __popcll(m & ((1ull << lane) - 1ull));
                if (pos < K) s_idx[wu][pos] = i;
            }
            cnt += __popcll(m);
        }
    }
    const int found = cnt < K ? cnt : K;
    const int first = (found > 0) ? s_idx[wu][0] : 0;
    const int id    = (lane < found) ? s_idx[wu][lane] : first;
    s_idx[wu][lane] = id;                  // padded list (same-wave use only)

    // ---- channels 0,1: grouped_xyz = xyz[id] - new_xyz[s] ----
    const size_t SK = (size_t)S * K;
    const float2 pxy = *(const float2*)&xb[(size_t)id * 2];
    {
        float* ob = out + ((size_t)b * OC) * SK + (size_t)s * K;
        ob[lane]      = pxy.x - qx;
        ob[SK + lane] = pxy.y - qy;
    }

    // ---- Phase 2: gather (4 lanes/row) -> LDS transpose -> 1KB stores ----
    const int kk = lane >> 2;              // gather: point-sub 0..15
    const int c2 = lane & 3;               // gather: float4 slot in 16-ch chunk
    const int ql = lane >> 4;              // store: query sub-index 0..3
    const int m  = lane & 15;              // store: k group
    const float* __restrict__ ftb = ft + (size_t)b * N * C;

    #pragma unroll
    for (int cc = 0; cc < 4; ++cc) {       // 16-channel chunks
        f32x4 v[4];
        #pragma unroll
        for (int g = 0; g < 4; ++g) {
            const int p  = g * 16 + kk;                 // point 0..63
            const int ip = s_idx[wu][p];                // 16 addrs, broadcast x4
            v[g] = *(const f32x4*)&ftb[(size_t)ip * C + cc * 16 + c2 * 4];
        }

        __syncthreads();   // previous chunk's tile reads are done
        #pragma unroll
        for (int g = 0; g < 4; ++g) {
            const int p = g * 16 + kk;
            *(f32x4*)&tile[wu * TP + p * 17 + c2 * 4] = v[g];   // b128, ~floor
        }
        __syncthreads();

        // wave stores 4 channels of the chunk; 1 instr = 1 KB contiguous
        #pragma unroll
        for (int j = 0; j < 4; ++j) {
            const int cw = 4 * wu + j;                  // channel in chunk
            f32x4 vv;
            vv.x = tile[ql * TP + (4 * m + 0) * 17 + cw];
            vv.y = tile[ql * TP + (4 * m + 1) * 17 + cw];
            vv.z = tile[ql * TP + (4 * m + 2) * 17 + cw];
            vv.w = tile[ql * TP + (4 * m + 3) * 17 + cw];
            float* bp = out + ((size_t)b * OC + 2 + cc * 16 + cw) * SK + (size_t)s0 * K;
            *(((f32x4*)bp) + lane) = vv;               // plain cached store
        }
    }
}

// ---------------------------------------------------------------------------
// Fallback (tiny ws): fused kernel gathering directly from (B,C,N) feat.
// ---------------------------------------------------------------------------
__global__ __launch_bounds__(256) void qag_fallback(const float* __restrict__ xyz,
                                                    const float* __restrict__ new_xyz,
                                                    const float* __restrict__ feat,
                                                    const int* __restrict__ pointsnum,
                                                    float* __restrict__ out) {
    __shared__ int s_idx[4][K];

    const int t    = threadIdx.x;
    const int lane = t & 63;
    const int wu   = __builtin_amdgcn_readfirstlane(t >> 6);
    const int q0   = blockIdx.x * 4;
    const int b    = q0 >> 11;
    const int q    = q0 + wu;
    const int s    = (q0 & (S - 1)) + wu;

    const float qx = new_xyz[(size_t)q * 2 + 0];
    const float qy = new_xyz[(size_t)q * 2 + 1];
    const float* __restrict__ xb = xyz + (size_t)b * N * 2;

    int pn = pointsnum[b];
    pn = pn < 0 ? 0 : (pn > N ? N : pn);
    int cnt = 0;
    for (int base = 0; base < pn && cnt < K; base += 256) {
        float2 p[4];
        #pragma unroll
        for (int u = 0; u < 4; ++u) {
            int i  = base + u * 64 + lane;
            int ic = i < N ? i : N - 1;
            p[u] = *(const float2*)&xb[(size_t)ic * 2];
        }
        #pragma unroll
        for (int u = 0; u < 4; ++u) {
            const int i = base + u * 64 + lane;
            bool ok = false;
            if (i < pn) {
                const float dx = __fsub_rn(qx, p[u].x);
                const float dy = __fsub_rn(qy, p[u].y);
                const float d2 = __fadd_rn(__fmul_rn(dx, dx), __fmul_rn(dy, dy));
                ok = d2 < R2;
            }
            const unsigned long long mm = __ballot(ok);
            if (ok) {
                const int pos = cnt + __popcll(mm & ((1ull << lane) - 1ull));
                if (pos < K) s_idx[wu][pos] = i;
            }
            cnt += __popcll(mm);
        }
    }
    const int found = cnt < K ? cnt : K;
    const int first = (found > 0) ? s_idx[wu][0] : 0;
    const int id    = (lane < found) ? s_idx[wu][lane] : first;

    const size_t SK = (size_t)S * K;
    const float2 pxy = *(const float2*)&xb[(size_t)id * 2];
    float* ob = out + ((size_t)b * OC) * SK + (size_t)s * K;
    ob[lane]      = pxy.x - qx;
    ob[SK + lane] = pxy.y - qy;

    const float* __restrict__ fb = feat + (size_t)b * C * N;
    for (int c = 0; c < C; ++c) {
        ob[(size_t)(2 + c) * SK + lane] = fb[(size_t)c * N + id];
    }
}

extern "C" void kernel_launch(void* const* d_in, const int* in_sizes, int n_in,
                              void* d_out, int out_size, void* d_ws, size_t ws_size,
                              hipStream_t stream) {
    const float* xyz       = (const float*)d_in[0];
    const float* new_xyz   = (const float*)d_in[1];
    const float* feat      = (const float*)d_in[2];
    const int*   pointsnum = (const int*)d_in[3];
    float*       out       = (float*)d_out;

    const size_t ft_bytes = (size_t)B * N * C * sizeof(float);    // 16.8 MB
    if (ws_size >= ft_bytes) {
        float* ft = (float*)d_ws;
        transpose_kernel<<<dim3(N / 64, B), 256, 0, stream>>>(feat, ft);
        qag2_kernel<<<B * S / 4, 256, 0, stream>>>(xyz, new_xyz, ft, pointsnum, out);
    } else {
        qag_fallback<<<B * S / 4, 256, 0, stream>>>(xyz, new_xyz, feat, pointsnum, out);
    }
}

// Round 9
// 48.519 us; speedup vs baseline: 1.2318x; 1.0773x over previous
//
#include <hip/hip_runtime.h>
#include <stdint.h>

#define B 4
#define N 16384
#define S 2048
#define C 64
#define K 64
#define OC 66
#define R2 0.01f
#define NXCD 8
#define TP 1089   // per-wave tile: 64 points x pitch 17 floats (+skew)

typedef float f32x4 __attribute__((ext_vector_type(4)));

// ---------------------------------------------------------------------------
// Kernel 1: transpose features (B,C,N) -> ft (B,N,C).
// ---------------------------------------------------------------------------
__global__ __launch_bounds__(256) void transpose_kernel(const float* __restrict__ f,
                                                        float* __restrict__ ft) {
    __shared__ float tile[64 * 65];
    const int n0 = blockIdx.x * 64;
    const int b  = blockIdx.y;
    const int t  = threadIdx.x;

    const int nl = t & 63, cl = t >> 6;
    #pragma unroll
    for (int cc = cl; cc < 64; cc += 4) {
        tile[cc * 65 + nl] = __builtin_nontemporal_load(&f[((size_t)b * C + cc) * N + n0 + nl]);
    }
    __syncthreads();

    const int cl2 = t & 63, nl2 = t >> 6;
    #pragma unroll
    for (int nn = nl2; nn < 64; nn += 4) {
        ft[((size_t)b * N + n0 + nn) * C + cl2] = tile[cl2 * 65 + nn];
    }
}

// ---------------------------------------------------------------------------
// Kernel 2: fused ball-query + group + concat. ZERO BARRIERS.
// Each wave owns one query end-to-end; LDS regions are wave-private, so no
// __syncthreads -> no s_waitcnt vmcnt(0) drains -> stores stay in flight
// continuously. Scan prefetches the next super-chunk so loads aren't
// serialized behind the cnt<K exit branch.
// ---------------------------------------------------------------------------
__global__ __launch_bounds__(256) void qag3_kernel(const float* __restrict__ xyz,
                                                   const float* __restrict__ new_xyz,
                                                   const float* __restrict__ ft,
                                                   const int* __restrict__ pointsnum,
                                                   float* __restrict__ out) {
    __shared__ int   s_idx[4][K];          // per-wave index list
    __shared__ float tile[4 * TP];         // per-wave private staging

    const int t    = threadIdx.x;
    const int lane = t & 63;
    const int wu   = __builtin_amdgcn_readfirstlane(t >> 6);

    // bijective XCD swizzle: nwg = 2048, 2048 % 8 == 0
    const int nwg = (B * S) / 4;
    const int bid = blockIdx.x;
    const int swz = (bid & (NXCD - 1)) * (nwg / NXCD) + (bid >> 3);

    const int q0 = swz * 4;
    const int b  = q0 >> 11;               // / S
    const int q  = q0 + wu;
    const int s  = (q0 & (S - 1)) + wu;

    const float qx = new_xyz[(size_t)q * 2 + 0];
    const float qy = new_xyz[(size_t)q * 2 + 1];
    const float* __restrict__ xb = xyz + (size_t)b * N * 2;

    // ---- Phase 1: ordered ball-query scan, next-chunk prefetch ----
    int pn = pointsnum[b];
    pn = pn < 0 ? 0 : (pn > N ? N : pn);
    int cnt = 0;
    float2 p[4], pf[4];
    #pragma unroll
    for (int u = 0; u < 4; ++u) {
        const int i  = u * 64 + lane;
        const int ic = i < N ? i : N - 1;
        p[u] = *(const float2*)&xb[(size_t)ic * 2];
    }
    for (int base = 0; base < pn && cnt < K; base += 256) {
        #pragma unroll
        for (int u = 0; u < 4; ++u) {       // prefetch next super-chunk
            const int i  = base + 256 + u * 64 + lane;
            const int ic = i < N ? i : N - 1;
            pf[u] = *(const float2*)&xb[(size_t)ic * 2];
        }
        #pragma unroll
        for (int u = 0; u < 4; ++u) {
            const int i = base + u * 64 + lane;
            bool ok = false;
            if (i < pn) {
                // match numpy f32 rounding exactly: no FMA contraction
                const float dx = __fsub_rn(qx, p[u].x);
                const float dy = __fsub_rn(qy, p[u].y);
                const float d2 = __fadd_rn(__fmul_rn(dx, dx), __fmul_rn(dy, dy));
                ok = d2 < R2;
            }
            const unsigned long long m = __ballot(ok);
            if (ok) {
                const int pos = cnt + __popcll(m & ((1ull << lane) - 1ull));
                if (pos < K) s_idx[wu][pos] = i;
            }
            cnt += __popcll(m);
        }
        #pragma unroll
        for (int u = 0; u < 4; ++u) p[u] = pf[u];
    }
    const int found = cnt < K ? cnt : K;
    const int first = (found > 0) ? s_idx[wu][0] : 0;
    const int id    = (lane < found) ? s_idx[wu][lane] : first;
    s_idx[wu][lane] = id;                  // padded list (same-wave use only)

    // ---- channels 0,1: grouped_xyz = xyz[id] - new_xyz[s] ----
    const size_t SK = (size_t)S * K;
    const float2 pxy = *(const float2*)&xb[(size_t)id * 2];
    float* ob = out + ((size_t)b * OC) * SK + (size_t)s * K;   // own query
    ob[lane]      = pxy.x - qx;
    ob[SK + lane] = pxy.y - qy;

    // ---- Phase 2: per-wave gather -> private LDS -> 256B cached stores ----
    const int kk = lane >> 2;              // point-sub 0..15
    const int c2 = lane & 3;               // float4 slot in 16-ch chunk
    const float* __restrict__ ftb = ft + (size_t)b * N * C;
    float* owt = tile + wu * TP;

    #pragma unroll
    for (int cc = 0; cc < 4; ++cc) {       // 16-channel chunks
        f32x4 v[4];
        #pragma unroll
        for (int g = 0; g < 4; ++g) {      // own query's 64 points, 16 rows/instr
            const int pt = g * 16 + kk;
            const int ip = s_idx[wu][pt];
            v[g] = *(const f32x4*)&ftb[(size_t)ip * C + cc * 16 + c2 * 4];
        }
        #pragma unroll
        for (int g = 0; g < 4; ++g) {
            const int pt = g * 16 + kk;
            *(f32x4*)&owt[pt * 17 + c2 * 4] = v[g];     // b128, skewed banks
        }
        // lane = k; 16 channels: ds_read stride 17 (2-way, free) + 256B store
        #pragma unroll
        for (int c = 0; c < 16; ++c) {
            const float vv = owt[lane * 17 + c];
            ob[(size_t)(2 + cc * 16 + c) * SK + lane] = vv;
        }
    }
}

// ---------------------------------------------------------------------------
// Fallback (tiny ws): fused kernel gathering directly from (B,C,N) feat.
// ---------------------------------------------------------------------------
__global__ __launch_bounds__(256) void qag_fallback(const float* __restrict__ xyz,
                                                    const float* __restrict__ new_xyz,
                                                    const float* __restrict__ feat,
                                                    const int* __restrict__ pointsnum,
                                                    float* __restrict__ out) {
    __shared__ int s_idx[4][K];

    const int t    = threadIdx.x;
    const int lane = t & 63;
    const int wu   = __builtin_amdgcn_readfirstlane(t >> 6);
    const int q0   = blockIdx.x * 4;
    const int b    = q0 >> 11;
    const int q    = q0 + wu;
    const int s    = (q0 & (S - 1)) + wu;

    const float qx = new_xyz[(size_t)q * 2 + 0];
    const float qy = new_xyz[(size_t)q * 2 + 1];
    const float* __restrict__ xb = xyz + (size_t)b * N * 2;

    int pn = pointsnum[b];
    pn = pn < 0 ? 0 : (pn > N ? N : pn);
    int cnt = 0;
    for (int base = 0; base < pn && cnt < K; base += 256) {
        float2 p[4];
        #pragma unroll
        for (int u = 0; u < 4; ++u) {
            int i  = base + u * 64 + lane;
            int ic = i < N ? i : N - 1;
            p[u] = *(const float2*)&xb[(size_t)ic * 2];
        }
        #pragma unroll
        for (int u = 0; u < 4; ++u) {
            const int i = base + u * 64 + lane;
            bool ok = false;
            if (i < pn) {
                const float dx = __fsub_rn(qx, p[u].x);
                const float dy = __fsub_rn(qy, p[u].y);
                const float d2 = __fadd_rn(__fmul_rn(dx, dx), __fmul_rn(dy, dy));
                ok = d2 < R2;
            }
            const unsigned long long mm = __ballot(ok);
            if (ok) {
                const int pos = cnt + __popcll(mm & ((1ull << lane) - 1ull));
                if (pos < K) s_idx[wu][pos] = i;
            }
            cnt += __popcll(mm);
        }
    }
    const int found = cnt < K ? cnt : K;
    const int first = (found > 0) ? s_idx[wu][0] : 0;
    const int id    = (lane < found) ? s_idx[wu][lane] : first;

    const size_t SK = (size_t)S * K;
    const float2 pxy = *(const float2*)&xb[(size_t)id * 2];
    float* ob = out + ((size_t)b * OC) * SK + (size_t)s * K;
    ob[lane]      = pxy.x - qx;
    ob[SK + lane] = pxy.y - qy;

    const float* __restrict__ fb = feat + (size_t)b * C * N;
    for (int c = 0; c < C; ++c) {
        ob[(size_t)(2 + c) * SK + lane] = fb[(size_t)c * N + id];
    }
}

extern "C" void kernel_launch(void* const* d_in, const int* in_sizes, int n_in,
                              void* d_out, int out_size, void* d_ws, size_t ws_size,
                              hipStream_t stream) {
    const float* xyz       = (const float*)d_in[0];
    const float* new_xyz   = (const float*)d_in[1];
    const float* feat      = (const float*)d_in[2];
    const int*   pointsnum = (const int*)d_in[3];
    float*       out       = (float*)d_out;

    const size_t ft_bytes = (size_t)B * N * C * sizeof(float);    // 16.8 MB
    if (ws_size >= ft_bytes) {
        float* ft = (float*)d_ws;
        transpose_kernel<<<dim3(N / 64, B), 256, 0, stream>>>(feat, ft);
        qag3_kernel<<<B * S / 4, 256, 0, stream>>>(xyz, new_xyz, ft, pointsnum, out);
    } else {
        qag_fallback<<<B * S / 4, 256, 0, stream>>>(xyz, new_xyz, feat, pointsnum, out);
    }
}